// Round 1
// baseline (593.699 us; speedup 1.0000x reference)
//
#include <hip/hip_runtime.h>
#include <hip/hip_bf16.h>
#include <math.h>

// AxialShift block (AS-MLP): conv1x1 -> GN(1) -> GELU -> 4 axial-shift conv1x1
// branches (gelu, summed) -> GN(1) -> conv1x1.  B=4, C=96, H=W=256, fp32.
//
// Round 0: correctness-first fp32 VALU implementation.
//  K0: transpose weights to [c][o] + zero stat accumulators
//  K1: y1 = conv1(x) + b1, partial sum/sumsq for GN1        (y1 -> ws)
//  K2: finalize GN1 mean/rstd
//  K3: stage a = gelu(gn1(y1)) in LDS halo tile (bf16), 4 shifted convs,
//      z = sum of gelus -> d_out, partial sums for GN2
//  K4: finalize GN2
//  K5: out = conv3(gn2(z)) in-place in d_out

#define B_ 4
#define C_ 96
#define H_ 256
#define W_ 256
#define NPIX (H_ * W_)
#define GN_N ((float)(C_ * NPIX))

__device__ __forceinline__ float gelu_f(float v) {
    return 0.5f * v * (1.0f + erff(v * 0.70710678118654752440f));
}

__device__ __forceinline__ float waveReduceSum(float v) {
#pragma unroll
    for (int off = 32; off > 0; off >>= 1) v += __shfl_down(v, off);
    return v;
}

// ---------------- K0: weight transpose + zero stats ----------------
__global__ void k0_prep(const float* __restrict__ w1, const float* __restrict__ w21,
                        const float* __restrict__ w22, const float* __restrict__ w3,
                        float* __restrict__ w1t, float* __restrict__ w21t,
                        float* __restrict__ w22t, float* __restrict__ w3t,
                        float* __restrict__ stats) {
    int t = blockIdx.x * 256 + threadIdx.x;
    if (blockIdx.x == 0 && threadIdx.x < 16) stats[threadIdx.x] = 0.f;
    if (t >= 4 * C_ * C_) return;
    int m = t / (C_ * C_);
    int r = t - m * (C_ * C_);
    int o = r / C_, c = r - (r / C_) * C_;
    const float* src = (m == 0) ? w1 : (m == 1) ? w21 : (m == 2) ? w22 : w3;
    float* dst = (m == 0) ? w1t : (m == 1) ? w21t : (m == 2) ? w22t : w3t;
    dst[c * C_ + o] = src[o * C_ + c];
}

// ---------------- K1: conv1 + GN1 partial stats ----------------
__global__ __launch_bounds__(256) void k1_conv1(
    const float* __restrict__ x, const float* __restrict__ w1t,
    const float* __restrict__ b1, float* __restrict__ y1,
    float* __restrict__ stats) {
    __shared__ float xs[C_ * 64];
    __shared__ float red[8];
    int b = blockIdx.x >> 10;
    int pix0 = (blockIdx.x & 1023) << 6;
    int tid = threadIdx.x;
    for (int t = tid; t < C_ * 64; t += 256) {
        int c = t >> 6, p = t & 63;
        xs[t] = x[(size_t)(b * C_ + c) * NPIX + pix0 + p];
    }
    __syncthreads();
    int o0 = __builtin_amdgcn_readfirstlane(24 * (tid >> 6));
    int l = tid & 63;
    float acc[24];
#pragma unroll
    for (int j = 0; j < 24; ++j) acc[j] = 0.f;
    for (int c = 0; c < C_; ++c) {
        float av = xs[(c << 6) + l];
        const float* wr = w1t + c * C_ + o0;
#pragma unroll
        for (int j = 0; j < 24; ++j) acc[j] += wr[j] * av;
    }
    float ls = 0.f, lsq = 0.f;
    size_t outbase = (size_t)(b * C_ + o0) * NPIX + pix0 + l;
#pragma unroll
    for (int j = 0; j < 24; ++j) {
        float y = acc[j] + b1[o0 + j];
        y1[outbase + (size_t)j * NPIX] = y;
        ls += y;
        lsq += y * y;
    }
    ls = waveReduceSum(ls);
    lsq = waveReduceSum(lsq);
    if (l == 0) { red[tid >> 6] = ls; red[4 + (tid >> 6)] = lsq; }
    __syncthreads();
    if (tid == 0) {
        atomicAdd(&stats[b], red[0] + red[1] + red[2] + red[3]);
        atomicAdd(&stats[4 + b], red[4] + red[5] + red[6] + red[7]);
    }
}

// ---------------- K2/K4: finalize GN stats ----------------
__global__ void k2_fin(float* stats, int so, int dof) {
    int t = threadIdx.x;
    if (t < 4) {
        float mean = stats[so + t] / GN_N;
        float var = stats[so + 4 + t] / GN_N - mean * mean;
        stats[dof + t] = mean;
        stats[dof + 4 + t] = rsqrtf(var + 1e-5f);
    }
}

// ---------------- K3: fused shifts + 4 convs + gelu-sum + GN2 stats --------
// variant shifts (output[h,w] = a[h-dh, w-dw], d = g-1, g = c/32):
//   v0 x_lr:     (0,  d)   v1 x_l_diag: (d, d)
//   v2 x_td:     (d,  0)   v3 x_r_diag: (d, -d)
__global__ __launch_bounds__(256) void k3_main(
    const float* __restrict__ y1,
    const float* __restrict__ w21t, const float* __restrict__ b21,
    const float* __restrict__ w22t, const float* __restrict__ b22,
    const float* __restrict__ gn1w, const float* __restrict__ gn1b,
    float* __restrict__ z, float* __restrict__ stats) {
    __shared__ __hip_bfloat16 as[C_ * 3 * 66];  // [c][r(3)][x(66)]
    __shared__ float red[8];
    int wseg = blockIdx.x & 3;
    int h = (blockIdx.x >> 2) & 255;
    int b = blockIdx.x >> 10;
    int w0 = wseg << 6;
    int tid = threadIdx.x;
    float m1 = stats[16 + b], r1 = stats[20 + b];
    for (int t = tid; t < C_ * 198; t += 256) {
        int c = t / 198;
        int rem = t - c * 198;
        int r = rem / 66;
        int xx = rem - r * 66;
        int hh = h - 1 + r;
        int ww = w0 - 1 + xx;
        float v = 0.f;
        if (hh >= 0 && hh < H_ && ww >= 0 && ww < W_) {
            float yv = y1[(size_t)(b * C_ + c) * NPIX + hh * W_ + ww];
            v = gelu_f((yv - m1) * r1 * gn1w[c] + gn1b[c]);
        }
        as[t] = __float2bfloat16(v);
    }
    __syncthreads();
    int o0 = __builtin_amdgcn_readfirstlane(24 * (tid >> 6));
    int l = tid & 63;
    int xl = l + 1;
    float acc0[24], acc1[24], acc2[24], acc3[24];
#pragma unroll
    for (int j = 0; j < 24; ++j) { acc0[j] = acc1[j] = acc2[j] = acc3[j] = 0.f; }
    for (int c = 0; c < C_; ++c) {
        int d = (c >> 5) - 1;
        int base = c * 198;
        float a0 = __bfloat162float(as[base + 66 + xl - d]);
        int rb = base + 66 - 66 * d;
        float a1 = __bfloat162float(as[rb + xl - d]);
        float a2 = __bfloat162float(as[rb + xl]);
        float a3 = __bfloat162float(as[rb + xl + d]);
        const float* wa = w21t + c * C_ + o0;
        const float* wb = w22t + c * C_ + o0;
#pragma unroll
        for (int j = 0; j < 24; ++j) {
            acc0[j] += wa[j] * a0;
            acc1[j] += wa[j] * a1;
            acc2[j] += wb[j] * a2;
            acc3[j] += wb[j] * a3;
        }
    }
    float ls = 0.f, lsq = 0.f;
    size_t outbase = (size_t)(b * C_ + o0) * NPIX + h * W_ + w0 + l;
#pragma unroll
    for (int j = 0; j < 24; ++j) {
        float bb1 = b21[o0 + j], bb2 = b22[o0 + j];
        float zv = gelu_f(acc0[j] + bb1) + gelu_f(acc1[j] + bb1) +
                   gelu_f(acc2[j] + bb2) + gelu_f(acc3[j] + bb2);
        z[outbase + (size_t)j * NPIX] = zv;
        ls += zv;
        lsq += zv * zv;
    }
    ls = waveReduceSum(ls);
    lsq = waveReduceSum(lsq);
    if (l == 0) { red[tid >> 6] = ls; red[4 + (tid >> 6)] = lsq; }
    __syncthreads();
    if (tid == 0) {
        atomicAdd(&stats[8 + b], red[0] + red[1] + red[2] + red[3]);
        atomicAdd(&stats[12 + b], red[4] + red[5] + red[6] + red[7]);
    }
}

// ---------------- K5: GN2 + conv3, in-place in d_out ----------------
__global__ __launch_bounds__(256) void k5_conv3(
    const float* __restrict__ w3t, const float* __restrict__ b3,
    const float* __restrict__ gn2w, const float* __restrict__ gn2b,
    float* __restrict__ zo, const float* __restrict__ stats) {
    __shared__ float zs[C_ * 64];
    int b = blockIdx.x >> 10;
    int pix0 = (blockIdx.x & 1023) << 6;
    int tid = threadIdx.x;
    float m2 = stats[24 + b], r2 = stats[28 + b];
    for (int t = tid; t < C_ * 64; t += 256) {
        int c = t >> 6, p = t & 63;
        float zv = zo[(size_t)(b * C_ + c) * NPIX + pix0 + p];
        zs[t] = (zv - m2) * r2 * gn2w[c] + gn2b[c];
    }
    __syncthreads();
    int o0 = __builtin_amdgcn_readfirstlane(24 * (tid >> 6));
    int l = tid & 63;
    float acc[24];
#pragma unroll
    for (int j = 0; j < 24; ++j) acc[j] = 0.f;
    for (int c = 0; c < C_; ++c) {
        float av = zs[(c << 6) + l];
        const float* wr = w3t + c * C_ + o0;
#pragma unroll
        for (int j = 0; j < 24; ++j) acc[j] += wr[j] * av;
    }
    // in-place: this block's pixels are read only by this block (staging done)
    size_t outbase = (size_t)(b * C_ + o0) * NPIX + pix0 + l;
#pragma unroll
    for (int j = 0; j < 24; ++j) zo[outbase + (size_t)j * NPIX] = acc[j] + b3[o0 + j];
}

extern "C" void kernel_launch(void* const* d_in, const int* in_sizes, int n_in,
                              void* d_out, int out_size, void* d_ws, size_t ws_size,
                              hipStream_t stream) {
    const float* x = (const float*)d_in[0];
    const float* w1 = (const float*)d_in[1];
    const float* b1 = (const float*)d_in[2];
    const float* w21 = (const float*)d_in[3];
    const float* b21 = (const float*)d_in[4];
    const float* w22 = (const float*)d_in[5];
    const float* b22 = (const float*)d_in[6];
    const float* w3 = (const float*)d_in[7];
    const float* b3 = (const float*)d_in[8];
    const float* gn1w = (const float*)d_in[9];
    const float* gn1b = (const float*)d_in[10];
    const float* gn2w = (const float*)d_in[11];
    const float* gn2b = (const float*)d_in[12];
    float* out = (float*)d_out;
    char* ws = (char*)d_ws;

    const size_t Y1B = (size_t)B_ * C_ * NPIX * sizeof(float);  // 100,663,296 B
    float* y1 = (float*)ws;
    float* stats = (float*)(ws + Y1B);          // 32 floats used
    float* w1t = (float*)(ws + Y1B + 128);
    float* w21t = w1t + C_ * C_;
    float* w22t = w21t + C_ * C_;
    float* w3t = w22t + C_ * C_;

    hipLaunchKernelGGL(k0_prep, dim3(144), dim3(256), 0, stream,
                       w1, w21, w22, w3, w1t, w21t, w22t, w3t, stats);
    hipLaunchKernelGGL(k1_conv1, dim3(4096), dim3(256), 0, stream, x, w1t, b1, y1, stats);
    hipLaunchKernelGGL(k2_fin, dim3(1), dim3(64), 0, stream, stats, 0, 16);
    hipLaunchKernelGGL(k3_main, dim3(4096), dim3(256), 0, stream,
                       y1, w21t, b21, w22t, b22, gn1w, gn1b, out, stats);
    hipLaunchKernelGGL(k2_fin, dim3(1), dim3(64), 0, stream, stats, 8, 24);
    hipLaunchKernelGGL(k5_conv3, dim3(4096), dim3(256), 0, stream,
                       w3t, b3, gn2w, gn2b, out, stats);
}

// Round 2
// 488.490 us; speedup vs baseline: 1.2154x; 1.2154x over previous
//
#include <hip/hip_runtime.h>
#include <hip/hip_bf16.h>
#include <math.h>

// AxialShift block: conv1x1 -> GN(1) -> GELU -> 4 axial-shift conv1x1 branches
// (gelu, summed) -> GN(1) -> conv1x1.  B=4, C=96, H=W=256, fp32 in/out.
// Round 2: MFMA (16x16x32 bf16) everywhere. Activations staged [pix][ch] bf16
// in LDS (CPAD=104 stride: 16B-aligned, ~2-way banks). K-step (32ch) == shift
// group, so each variant is just a shifted B-frag address.

#define B_ 4
#define C_ 96
#define H_ 256
#define W_ 256
#define NPIX (H_ * W_)
#define GN_N ((float)(C_ * NPIX))
#define CPAD 104

#define HT 8
#define WT 32
#define HHT (HT + 2)
#define HWT (WT + 2)

typedef __attribute__((ext_vector_type(4))) float f32x4;
typedef __attribute__((ext_vector_type(8))) short short8;

__device__ __forceinline__ unsigned short f2bf(float v) {
    unsigned int u = __float_as_uint(v);
    unsigned int r = (u + 0x7FFFu + ((u >> 16) & 1u)) >> 16;
    return (unsigned short)r;
}

__device__ __forceinline__ float gelu_f(float v) {
    // tanh-approx gelu: 0.5v(1+tanh(0.79788456 v (1+0.044715 v^2)))
    //                 = v * (1 - 1/(exp(2u)+1)); safe at +-inf
    float u2 = 1.5957691216057308f * v * (1.0f + 0.044715f * v * v);
    float e = __expf(u2);
    return v * (1.0f - 1.0f / (e + 1.0f));
}

__device__ __forceinline__ float waveReduceSum(float v) {
#pragma unroll
    for (int off = 32; off > 0; off >>= 1) v += __shfl_down(v, off);
    return v;
}

__device__ __forceinline__ f32x4 mfma16(short8 a, short8 b, f32x4 c) {
    return __builtin_amdgcn_mfma_f32_16x16x32_bf16(a, b, c, 0, 0, 0);
}

// ---------------- K0: weights -> bf16 [o][c], zero stats ----------------
__global__ void k0_prep(const float* __restrict__ w1, const float* __restrict__ w21,
                        const float* __restrict__ w22, const float* __restrict__ w3,
                        unsigned short* __restrict__ wb, float* __restrict__ stats) {
    int t = blockIdx.x * 256 + threadIdx.x;
    if (blockIdx.x == 0 && threadIdx.x < 16) stats[threadIdx.x] = 0.f;
    if (t >= 4 * C_ * C_) return;
    int m = t / (C_ * C_);
    int r = t - m * (C_ * C_);
    const float* src = (m == 0) ? w1 : (m == 1) ? w21 : (m == 2) ? w22 : w3;
    wb[t] = f2bf(src[r]);
}

// ---------------- K1: conv1 (MFMA) + GN1 partial stats ----------------
__global__ __launch_bounds__(256) void k1_conv1(
    const float* __restrict__ x, const unsigned short* __restrict__ w1b,
    const float* __restrict__ b1, float* __restrict__ y1,
    float* __restrict__ stats) {
    __shared__ unsigned short xs[256 * CPAD];
    __shared__ float red[8];
    int tid = threadIdx.x;
    int b = blockIdx.x >> 8;
    int pix0 = (blockIdx.x & 255) << 8;
    // stage: thread = pixel, loop channels; [pix][ch] bf16
    size_t xbase = (size_t)b * C_ * NPIX + pix0 + tid;
    int lb = tid * CPAD;
    for (int c0 = 0; c0 < C_; c0 += 8) {
        short8 pk;
#pragma unroll
        for (int j = 0; j < 8; ++j)
            pk[j] = (short)f2bf(x[xbase + (size_t)(c0 + j) * NPIX]);
        *reinterpret_cast<short8*>(&xs[lb + c0]) = pk;
    }
    __syncthreads();
    int l = tid & 63, wv = tid >> 6;
    int bx = l & 15, cl = (l >> 4) * 8;
    // B-frags invariant across m-tiles: preload 12
    short8 bfr[4][3];
#pragma unroll
    for (int nf = 0; nf < 4; ++nf) {
        int p = (4 * wv + nf) * 16 + bx;
#pragma unroll
        for (int kb = 0; kb < 3; ++kb)
            bfr[nf][kb] = *reinterpret_cast<const short8*>(&xs[p * CPAD + kb * 32 + cl]);
    }
    float ls = 0.f, lsq = 0.f;
    for (int mt = 0; mt < 6; ++mt) {
        int m0 = mt * 16;
        const unsigned short* wp = w1b + (m0 + bx) * C_ + cl;
        short8 af[3];
#pragma unroll
        for (int kb = 0; kb < 3; ++kb)
            af[kb] = *reinterpret_cast<const short8*>(wp + kb * 32);
        f32x4 acc[4];
#pragma unroll
        for (int nf = 0; nf < 4; ++nf) acc[nf] = (f32x4){0.f, 0.f, 0.f, 0.f};
#pragma unroll
        for (int nf = 0; nf < 4; ++nf)
#pragma unroll
            for (int kb = 0; kb < 3; ++kb)
                acc[nf] = mfma16(af[kb], bfr[nf][kb], acc[nf]);
#pragma unroll
        for (int nf = 0; nf < 4; ++nf) {
            int p = pix0 + (4 * wv + nf) * 16 + bx;
            size_t ob0 = (size_t)(b * C_ + m0 + (l >> 4) * 4) * NPIX + p;
#pragma unroll
            for (int rg = 0; rg < 4; ++rg) {
                float y = acc[nf][rg] + b1[m0 + (l >> 4) * 4 + rg];
                y1[ob0 + (size_t)rg * NPIX] = y;
                ls += y;
                lsq += y * y;
            }
        }
    }
    ls = waveReduceSum(ls);
    lsq = waveReduceSum(lsq);
    if (l == 0) { red[wv] = ls; red[4 + wv] = lsq; }
    __syncthreads();
    if (tid == 0) {
        atomicAdd(&stats[b], red[0] + red[1] + red[2] + red[3]);
        atomicAdd(&stats[4 + b], red[4] + red[5] + red[6] + red[7]);
    }
}

// ---------------- K2/K4: finalize GN stats ----------------
__global__ void k2_fin(float* stats, int so, int dof) {
    int t = threadIdx.x;
    if (t < 4) {
        float mean = stats[so + t] / GN_N;
        float var = stats[so + 4 + t] / GN_N - mean * mean;
        stats[dof + t] = mean;
        stats[dof + 4 + t] = rsqrtf(var + 1e-5f);
    }
}

// ---------------- K3: fused shifts + 4 convs (MFMA) + gelu-sum + GN2 stats --
// shifts (s = kb-1): v0 a[h][w-s]  v1 a[h-s][w-s]  v2 a[h-s][w]  v3 a[h-s][w+s]
__global__ __launch_bounds__(256) void k3_main(
    const float* __restrict__ y1,
    const unsigned short* __restrict__ w21b, const float* __restrict__ b21,
    const unsigned short* __restrict__ w22b, const float* __restrict__ b22,
    const float* __restrict__ gn1w, const float* __restrict__ gn1b,
    float* __restrict__ z, float* __restrict__ stats) {
    __shared__ unsigned short as[HHT * HWT * CPAD];  // 10*34*104*2 = 70720 B
    __shared__ float red[8];
    int tid = threadIdx.x;
    int wseg = blockIdx.x & 7;
    int hseg = (blockIdx.x >> 3) & 31;
    int b = blockIdx.x >> 8;
    int h0 = hseg * HT, w0 = wseg * WT;
    float m1 = stats[16 + b], r1 = stats[20 + b];
    // stage halo tile: gelu(gn1(y1)) -> bf16 [halopix][ch]
    for (int hp = tid; hp < HHT * HWT; hp += 256) {
        int R = hp / HWT, X = hp - R * HWT;
        int hh = h0 - 1 + R, ww = w0 - 1 + X;
        bool valid = (hh >= 0 && hh < H_ && ww >= 0 && ww < W_);
        size_t gbase = (size_t)b * C_ * NPIX + (size_t)(hh * W_ + ww);
        int lb = hp * CPAD;
        for (int c0 = 0; c0 < C_; c0 += 8) {
            short8 pk;
#pragma unroll
            for (int j = 0; j < 8; ++j) {
                int c = c0 + j;
                float v = 0.f;
                if (valid) {
                    float sc = r1 * gn1w[c];
                    float off = gn1b[c] - m1 * sc;
                    v = gelu_f(fmaf(y1[gbase + (size_t)c * NPIX], sc, off));
                }
                pk[j] = (short)f2bf(v);
            }
            *reinterpret_cast<short8*>(&as[lb + c0]) = pk;
        }
    }
    __syncthreads();
    int l = tid & 63, wv = tid >> 6;
    int bx = l & 15, cl = (l >> 4) * 8;
    float ls = 0.f, lsq = 0.f;
    for (int mt = 0; mt < 6; ++mt) {
        int m0 = mt * 16;
        const unsigned short* wpa = w21b + (m0 + bx) * C_ + cl;
        const unsigned short* wpb = w22b + (m0 + bx) * C_ + cl;
        short8 aA[3], aB[3];
#pragma unroll
        for (int kb = 0; kb < 3; ++kb) {
            aA[kb] = *reinterpret_cast<const short8*>(wpa + kb * 32);
            aB[kb] = *reinterpret_cast<const short8*>(wpb + kb * 32);
        }
        f32x4 acc[4][4];  // [variant][nfrag]
#pragma unroll
        for (int v = 0; v < 4; ++v)
#pragma unroll
            for (int nf = 0; nf < 4; ++nf) acc[v][nf] = (f32x4){0.f, 0.f, 0.f, 0.f};
#pragma unroll
        for (int nf = 0; nf < 4; ++nf) {
            int r = 2 * wv + (nf >> 1);
            int X0 = (nf & 1) * 16 + bx + 1;  // halo x of this lane's pixel
#pragma unroll
            for (int kb = 0; kb < 3; ++kb) {
                const int s = kb - 1;
                int R0 = r + 1, RS = r + 1 - s;
                int co = kb * 32 + cl;
                short8 f0 = *reinterpret_cast<const short8*>(&as[(R0 * HWT + X0 - s) * CPAD + co]);
                short8 f1 = *reinterpret_cast<const short8*>(&as[(RS * HWT + X0 - s) * CPAD + co]);
                short8 f2 = *reinterpret_cast<const short8*>(&as[(RS * HWT + X0) * CPAD + co]);
                short8 f3 = *reinterpret_cast<const short8*>(&as[(RS * HWT + X0 + s) * CPAD + co]);
                acc[0][nf] = mfma16(aA[kb], f0, acc[0][nf]);
                acc[1][nf] = mfma16(aA[kb], f1, acc[1][nf]);
                acc[2][nf] = mfma16(aB[kb], f2, acc[2][nf]);
                acc[3][nf] = mfma16(aB[kb], f3, acc[3][nf]);
            }
        }
#pragma unroll
        for (int nf = 0; nf < 4; ++nf) {
            int r = 2 * wv + (nf >> 1);
            int xq = (nf & 1) * 16 + bx;
            size_t ob0 = (size_t)(b * C_ + m0 + (l >> 4) * 4) * NPIX +
                         (size_t)((h0 + r) * W_ + w0 + xq);
#pragma unroll
            for (int rg = 0; rg < 4; ++rg) {
                int o = m0 + (l >> 4) * 4 + rg;
                float bb1 = b21[o], bb2 = b22[o];
                float zv = gelu_f(acc[0][nf][rg] + bb1) + gelu_f(acc[1][nf][rg] + bb1) +
                           gelu_f(acc[2][nf][rg] + bb2) + gelu_f(acc[3][nf][rg] + bb2);
                z[ob0 + (size_t)rg * NPIX] = zv;
                ls += zv;
                lsq += zv * zv;
            }
        }
    }
    ls = waveReduceSum(ls);
    lsq = waveReduceSum(lsq);
    if (l == 0) { red[wv] = ls; red[4 + wv] = lsq; }
    __syncthreads();
    if (tid == 0) {
        atomicAdd(&stats[8 + b], red[0] + red[1] + red[2] + red[3]);
        atomicAdd(&stats[12 + b], red[4] + red[5] + red[6] + red[7]);
    }
}

// ---------------- K5: GN2 affine + conv3 (MFMA), in-place in d_out ---------
__global__ __launch_bounds__(256) void k5_conv3(
    const unsigned short* __restrict__ w3b, const float* __restrict__ b3,
    const float* __restrict__ gn2w, const float* __restrict__ gn2b,
    float* __restrict__ zo, const float* __restrict__ stats) {
    __shared__ unsigned short zs[256 * CPAD];
    int tid = threadIdx.x;
    int b = blockIdx.x >> 8;
    int pix0 = (blockIdx.x & 255) << 8;
    float m2 = stats[24 + b], r2 = stats[28 + b];
    size_t zbase = (size_t)b * C_ * NPIX + pix0 + tid;
    int lb = tid * CPAD;
    for (int c0 = 0; c0 < C_; c0 += 8) {
        short8 pk;
#pragma unroll
        for (int j = 0; j < 8; ++j) {
            int c = c0 + j;
            float sc = r2 * gn2w[c];
            float off = gn2b[c] - m2 * sc;
            pk[j] = (short)f2bf(fmaf(zo[zbase + (size_t)c * NPIX], sc, off));
        }
        *reinterpret_cast<short8*>(&zs[lb + c0]) = pk;
    }
    __syncthreads();
    int l = tid & 63, wv = tid >> 6;
    int bx = l & 15, cl = (l >> 4) * 8;
    short8 bfr[4][3];
#pragma unroll
    for (int nf = 0; nf < 4; ++nf) {
        int p = (4 * wv + nf) * 16 + bx;
#pragma unroll
        for (int kb = 0; kb < 3; ++kb)
            bfr[nf][kb] = *reinterpret_cast<const short8*>(&zs[p * CPAD + kb * 32 + cl]);
    }
    for (int mt = 0; mt < 6; ++mt) {
        int m0 = mt * 16;
        const unsigned short* wp = w3b + (m0 + bx) * C_ + cl;
        short8 af[3];
#pragma unroll
        for (int kb = 0; kb < 3; ++kb)
            af[kb] = *reinterpret_cast<const short8*>(wp + kb * 32);
        f32x4 acc[4];
#pragma unroll
        for (int nf = 0; nf < 4; ++nf) acc[nf] = (f32x4){0.f, 0.f, 0.f, 0.f};
#pragma unroll
        for (int nf = 0; nf < 4; ++nf)
#pragma unroll
            for (int kb = 0; kb < 3; ++kb)
                acc[nf] = mfma16(af[kb], bfr[nf][kb], acc[nf]);
#pragma unroll
        for (int nf = 0; nf < 4; ++nf) {
            int p = pix0 + (4 * wv + nf) * 16 + bx;
            size_t ob0 = (size_t)(b * C_ + m0 + (l >> 4) * 4) * NPIX + p;
#pragma unroll
            for (int rg = 0; rg < 4; ++rg)
                zo[ob0 + (size_t)rg * NPIX] = acc[nf][rg] + b3[m0 + (l >> 4) * 4 + rg];
        }
    }
}

extern "C" void kernel_launch(void* const* d_in, const int* in_sizes, int n_in,
                              void* d_out, int out_size, void* d_ws, size_t ws_size,
                              hipStream_t stream) {
    const float* x = (const float*)d_in[0];
    const float* w1 = (const float*)d_in[1];
    const float* b1 = (const float*)d_in[2];
    const float* w21 = (const float*)d_in[3];
    const float* b21 = (const float*)d_in[4];
    const float* w22 = (const float*)d_in[5];
    const float* b22 = (const float*)d_in[6];
    const float* w3 = (const float*)d_in[7];
    const float* b3 = (const float*)d_in[8];
    const float* gn1w = (const float*)d_in[9];
    const float* gn1b = (const float*)d_in[10];
    const float* gn2w = (const float*)d_in[11];
    const float* gn2b = (const float*)d_in[12];
    float* out = (float*)d_out;
    char* ws = (char*)d_ws;

    const size_t Y1B = (size_t)B_ * C_ * NPIX * sizeof(float);  // 100,663,296 B
    float* y1 = (float*)ws;
    float* stats = (float*)(ws + Y1B);  // 32 floats
    unsigned short* wb = (unsigned short*)(ws + Y1B + 128);
    unsigned short* w1b = wb;
    unsigned short* w21b = wb + C_ * C_;
    unsigned short* w22b = wb + 2 * C_ * C_;
    unsigned short* w3b = wb + 3 * C_ * C_;

    hipLaunchKernelGGL(k0_prep, dim3(144), dim3(256), 0, stream,
                       w1, w21, w22, w3, wb, stats);
    hipLaunchKernelGGL(k1_conv1, dim3(1024), dim3(256), 0, stream, x, w1b, b1, y1, stats);
    hipLaunchKernelGGL(k2_fin, dim3(1), dim3(64), 0, stream, stats, 0, 16);
    hipLaunchKernelGGL(k3_main, dim3(1024), dim3(256), 0, stream,
                       y1, w21b, b21, w22b, b22, gn1w, gn1b, out, stats);
    hipLaunchKernelGGL(k2_fin, dim3(1), dim3(64), 0, stream, stats, 8, 24);
    hipLaunchKernelGGL(k5_conv3, dim3(1024), dim3(256), 0, stream,
                       w3b, b3, gn2w, gn2b, out, stats);
}

// Round 3
// 263.064 us; speedup vs baseline: 2.2569x; 1.8569x over previous
//
#include <hip/hip_runtime.h>
#include <hip/hip_bf16.h>
#include <math.h>

// AxialShift block: conv1x1 -> GN(1) -> GELU -> 4 axial-shift conv1x1 branches
// (gelu, summed) -> GN(1) -> conv1x1.  B=4, C=96, H=W=256, fp32 in/out.
// Round 3: intermediates y1/z stored NHWC bf16 ([pix][96ch], 192B contiguous
// per pixel) so k3/k5 staging reads are big contiguous b128s instead of
// 4B-strided NCHW gather (round 2 was latency-bound at 5% HBM).

#define B_ 4
#define C_ 96
#define H_ 256
#define W_ 256
#define NPIX (H_ * W_)
#define GN_N ((float)(C_ * NPIX))
#define CPAD 104  // LDS ch stride (shorts): 208B, 16B-aligned, ~2-way banks

#define HT 8
#define WT 32
#define HHT (HT + 2)
#define HWT (WT + 2)

typedef __attribute__((ext_vector_type(4))) float f32x4;
typedef __attribute__((ext_vector_type(8))) short short8;

__device__ __forceinline__ unsigned short f2bf(float v) {
    unsigned int u = __float_as_uint(v);
    unsigned int r = (u + 0x7FFFu + ((u >> 16) & 1u)) >> 16;
    return (unsigned short)r;
}
__device__ __forceinline__ float bf2f(unsigned short u) {
    return __uint_as_float(((unsigned int)u) << 16);
}

__device__ __forceinline__ float gelu_f(float v) {
    // tanh-approx gelu = v * (1 - 1/(exp(2u)+1)); safe at +-inf
    float u2 = 1.5957691216057308f * v * (1.0f + 0.044715f * v * v);
    float e = __expf(u2);
    return v * (1.0f - 1.0f / (e + 1.0f));
}

__device__ __forceinline__ float waveReduceSum(float v) {
#pragma unroll
    for (int off = 32; off > 0; off >>= 1) v += __shfl_down(v, off);
    return v;
}

__device__ __forceinline__ f32x4 mfma16(short8 a, short8 b, f32x4 c) {
    return __builtin_amdgcn_mfma_f32_16x16x32_bf16(a, b, c, 0, 0, 0);
}

// ---------------- K0: weights -> bf16 [o][c], zero stats ----------------
__global__ void k0_prep(const float* __restrict__ w1, const float* __restrict__ w21,
                        const float* __restrict__ w22, const float* __restrict__ w3,
                        unsigned short* __restrict__ wb, float* __restrict__ stats) {
    int t = blockIdx.x * 256 + threadIdx.x;
    if (blockIdx.x == 0 && threadIdx.x < 16) stats[threadIdx.x] = 0.f;
    if (t >= 4 * C_ * C_) return;
    int m = t / (C_ * C_);
    int r = t - m * (C_ * C_);
    const float* src = (m == 0) ? w1 : (m == 1) ? w21 : (m == 2) ? w22 : w3;
    wb[t] = f2bf(src[r]);
}

// ---------------- K1: conv1 (MFMA) + GN1 stats -> y1b NHWC bf16 ------------
__global__ __launch_bounds__(256) void k1_conv1(
    const float* __restrict__ x, const unsigned short* __restrict__ w1b,
    const float* __restrict__ b1, unsigned short* __restrict__ y1b,
    float* __restrict__ stats) {
    __shared__ unsigned short xs[256 * CPAD];
    __shared__ float red[8];
    int tid = threadIdx.x;
    int b = blockIdx.x >> 8;
    int pix0 = (blockIdx.x & 255) << 8;
    size_t xbase = (size_t)b * C_ * NPIX + pix0 + tid;
    int lb = tid * CPAD;
    for (int c0 = 0; c0 < C_; c0 += 8) {
        short8 pk;
#pragma unroll
        for (int j = 0; j < 8; ++j)
            pk[j] = (short)f2bf(x[xbase + (size_t)(c0 + j) * NPIX]);
        *reinterpret_cast<short8*>(&xs[lb + c0]) = pk;
    }
    __syncthreads();
    int l = tid & 63, wv = tid >> 6;
    int bx = l & 15, cl = (l >> 4) * 8, q = l >> 4;
    short8 bfr[4][3];
#pragma unroll
    for (int nf = 0; nf < 4; ++nf) {
        int p = (4 * wv + nf) * 16 + bx;
#pragma unroll
        for (int kb = 0; kb < 3; ++kb)
            bfr[nf][kb] = *reinterpret_cast<const short8*>(&xs[p * CPAD + kb * 32 + cl]);
    }
    unsigned int* xsu = reinterpret_cast<unsigned int*>(xs);
    float ls = 0.f, lsq = 0.f;
    for (int mt = 0; mt < 6; ++mt) {
        int m0 = mt * 16;
        const unsigned short* wp = w1b + (m0 + bx) * C_ + cl;
        short8 af[3];
#pragma unroll
        for (int kb = 0; kb < 3; ++kb)
            af[kb] = *reinterpret_cast<const short8*>(wp + kb * 32);
        f32x4 acc[4];
#pragma unroll
        for (int nf = 0; nf < 4; ++nf) acc[nf] = (f32x4){0.f, 0.f, 0.f, 0.f};
#pragma unroll
        for (int nf = 0; nf < 4; ++nf)
#pragma unroll
            for (int kb = 0; kb < 3; ++kb)
                acc[nf] = mfma16(af[kb], bfr[nf][kb], acc[nf]);
        int o = m0 + q * 4;
        float b0 = b1[o], b1v = b1[o + 1], b2v = b1[o + 2], b3v = b1[o + 3];
#pragma unroll
        for (int nf = 0; nf < 4; ++nf) {
            int p = (4 * wv + nf) * 16 + bx;  // local pixel (own wave stripe)
            float y0 = acc[nf][0] + b0, y1v = acc[nf][1] + b1v;
            float y2 = acc[nf][2] + b2v, y3 = acc[nf][3] + b3v;
            ls += y0 + y1v + y2 + y3;
            lsq += y0 * y0 + y1v * y1v + y2 * y2 + y3 * y3;
            xsu[p * (CPAD / 2) + (o >> 1)] =
                (unsigned int)f2bf(y0) | ((unsigned int)f2bf(y1v) << 16);
            xsu[p * (CPAD / 2) + (o >> 1) + 1] =
                (unsigned int)f2bf(y2) | ((unsigned int)f2bf(y3) << 16);
        }
    }
    __syncthreads();
    size_t ybase = (size_t)(b * NPIX + pix0 + tid) * C_;
#pragma unroll
    for (int c0 = 0; c0 < C_; c0 += 8)
        *reinterpret_cast<short8*>(&y1b[ybase + c0]) =
            *reinterpret_cast<short8*>(&xs[tid * CPAD + c0]);
    ls = waveReduceSum(ls);
    lsq = waveReduceSum(lsq);
    if (l == 0) { red[wv] = ls; red[4 + wv] = lsq; }
    __syncthreads();
    if (tid == 0) {
        atomicAdd(&stats[b], red[0] + red[1] + red[2] + red[3]);
        atomicAdd(&stats[4 + b], red[4] + red[5] + red[6] + red[7]);
    }
}

// ---------------- K2/K4: finalize GN stats ----------------
__global__ void k2_fin(float* stats, int so, int dof) {
    int t = threadIdx.x;
    if (t < 4) {
        float mean = stats[so + t] / GN_N;
        float var = stats[so + 4 + t] / GN_N - mean * mean;
        stats[dof + t] = mean;
        stats[dof + 4 + t] = rsqrtf(var + 1e-5f);
    }
}

// ---------------- K3: shifts + 4 convs (MFMA) + gelu-sum -> zb NHWC --------
// shifts (s = kb-1): v0 a[h][w-s]  v1 a[h-s][w-s]  v2 a[h-s][w]  v3 a[h-s][w+s]
__global__ __launch_bounds__(256) void k3_main(
    const unsigned short* __restrict__ y1b,
    const unsigned short* __restrict__ w21b, const float* __restrict__ b21,
    const unsigned short* __restrict__ w22b, const float* __restrict__ b22,
    const float* __restrict__ gn1w, const float* __restrict__ gn1b,
    unsigned short* __restrict__ zb, float* __restrict__ stats) {
    __shared__ unsigned short as[HHT * HWT * CPAD];  // 70720 B
    __shared__ float red[8];
    __shared__ float scs[C_], offs[C_];
    int tid = threadIdx.x;
    int wseg = blockIdx.x & 7;
    int hseg = (blockIdx.x >> 3) & 31;
    int b = blockIdx.x >> 8;
    int h0 = hseg * HT, w0 = wseg * WT;
    float m1 = stats[16 + b], r1 = stats[20 + b];
    if (tid < C_) {
        float sc = r1 * gn1w[tid];
        scs[tid] = sc;
        offs[tid] = gn1b[tid] - m1 * sc;
    }
    __syncthreads();
    // stage halo: contiguous NHWC loads, gelu(affine) in regs -> LDS
    for (int hp = tid; hp < HHT * HWT; hp += 256) {
        int R = hp / HWT, X = hp - R * HWT;
        int hh = h0 - 1 + R, ww = w0 - 1 + X;
        int lb = hp * CPAD;
        if (hh >= 0 && hh < H_ && ww >= 0 && ww < W_) {
            const short8* src = reinterpret_cast<const short8*>(
                &y1b[(size_t)(b * NPIX + hh * W_ + ww) * C_]);
            short8 raw[12];
#pragma unroll
            for (int i = 0; i < 12; ++i) raw[i] = src[i];
#pragma unroll
            for (int i = 0; i < 12; ++i) {
                short8 pk;
#pragma unroll
                for (int j = 0; j < 8; ++j) {
                    int c = i * 8 + j;
                    float f = bf2f((unsigned short)raw[i][j]);
                    pk[j] = (short)f2bf(gelu_f(fmaf(f, scs[c], offs[c])));
                }
                *reinterpret_cast<short8*>(&as[lb + i * 8]) = pk;
            }
        } else {
            short8 zz = (short8){0, 0, 0, 0, 0, 0, 0, 0};
#pragma unroll
            for (int i = 0; i < 12; ++i)
                *reinterpret_cast<short8*>(&as[lb + i * 8]) = zz;
        }
    }
    __syncthreads();
    int l = tid & 63, wv = tid >> 6;
    int bx = l & 15, cl = (l >> 4) * 8, q = l >> 4;
    float ls = 0.f, lsq = 0.f;
    unsigned int zp[6][4][2];  // packed bf16 z, static-indexed
    for (int mt = 0; mt < 6; ++mt) {
        int m0 = mt * 16;
        const unsigned short* wpa = w21b + (m0 + bx) * C_ + cl;
        const unsigned short* wpb = w22b + (m0 + bx) * C_ + cl;
        short8 aA[3], aB[3];
#pragma unroll
        for (int kb = 0; kb < 3; ++kb) {
            aA[kb] = *reinterpret_cast<const short8*>(wpa + kb * 32);
            aB[kb] = *reinterpret_cast<const short8*>(wpb + kb * 32);
        }
        f32x4 acc[4][4];
#pragma unroll
        for (int v = 0; v < 4; ++v)
#pragma unroll
            for (int nf = 0; nf < 4; ++nf) acc[v][nf] = (f32x4){0.f, 0.f, 0.f, 0.f};
#pragma unroll
        for (int nf = 0; nf < 4; ++nf) {
            int r = 2 * wv + (nf >> 1);
            int X0 = (nf & 1) * 16 + bx + 1;
#pragma unroll
            for (int kb = 0; kb < 3; ++kb) {
                const int s = kb - 1;
                int R0 = r + 1, RS = r + 1 - s;
                int co = kb * 32 + cl;
                short8 f0 = *reinterpret_cast<const short8*>(&as[(R0 * HWT + X0 - s) * CPAD + co]);
                short8 f1 = *reinterpret_cast<const short8*>(&as[(RS * HWT + X0 - s) * CPAD + co]);
                short8 f2 = *reinterpret_cast<const short8*>(&as[(RS * HWT + X0) * CPAD + co]);
                short8 f3 = *reinterpret_cast<const short8*>(&as[(RS * HWT + X0 + s) * CPAD + co]);
                acc[0][nf] = mfma16(aA[kb], f0, acc[0][nf]);
                acc[1][nf] = mfma16(aA[kb], f1, acc[1][nf]);
                acc[2][nf] = mfma16(aB[kb], f2, acc[2][nf]);
                acc[3][nf] = mfma16(aB[kb], f3, acc[3][nf]);
            }
        }
        int o = m0 + q * 4;
#pragma unroll
        for (int nf = 0; nf < 4; ++nf) {
            float zv[4];
#pragma unroll
            for (int rg = 0; rg < 4; ++rg) {
                float bb1 = b21[o + rg], bb2 = b22[o + rg];
                float z0 = gelu_f(acc[0][nf][rg] + bb1) + gelu_f(acc[1][nf][rg] + bb1) +
                           gelu_f(acc[2][nf][rg] + bb2) + gelu_f(acc[3][nf][rg] + bb2);
                zv[rg] = z0;
                ls += z0;
                lsq += z0 * z0;
            }
            zp[mt][nf][0] = (unsigned int)f2bf(zv[0]) | ((unsigned int)f2bf(zv[1]) << 16);
            zp[mt][nf][1] = (unsigned int)f2bf(zv[2]) | ((unsigned int)f2bf(zv[3]) << 16);
        }
    }
    __syncthreads();  // all halo reads done; reuse `as` as transpose buffer
    unsigned int* asu = reinterpret_cast<unsigned int*>(as);
#pragma unroll
    for (int mt = 0; mt < 6; ++mt) {
        int o = mt * 16 + q * 4;
#pragma unroll
        for (int nf = 0; nf < 4; ++nf) {
            int r = 2 * wv + (nf >> 1);
            int xq = (nf & 1) * 16 + bx;
            int p = r * WT + xq;
            asu[p * (CPAD / 2) + (o >> 1)] = zp[mt][nf][0];
            asu[p * (CPAD / 2) + (o >> 1) + 1] = zp[mt][nf][1];
        }
    }
    __syncthreads();
    int gp = (h0 + (tid >> 5)) * W_ + w0 + (tid & 31);
    size_t zbase = (size_t)(b * NPIX + gp) * C_;
#pragma unroll
    for (int c0 = 0; c0 < C_; c0 += 8)
        *reinterpret_cast<short8*>(&zb[zbase + c0]) =
            *reinterpret_cast<short8*>(&as[tid * CPAD + c0]);
    ls = waveReduceSum(ls);
    lsq = waveReduceSum(lsq);
    if (l == 0) { red[wv] = ls; red[4 + wv] = lsq; }
    __syncthreads();
    if (tid == 0) {
        atomicAdd(&stats[8 + b], red[0] + red[1] + red[2] + red[3]);
        atomicAdd(&stats[12 + b], red[4] + red[5] + red[6] + red[7]);
    }
}

// ---------------- K5: GN2 affine + conv3 (MFMA) -> d_out NCHW fp32 ---------
__global__ __launch_bounds__(256) void k5_conv3(
    const unsigned short* __restrict__ zb,
    const unsigned short* __restrict__ w3b, const float* __restrict__ b3,
    const float* __restrict__ gn2w, const float* __restrict__ gn2b,
    float* __restrict__ out, const float* __restrict__ stats) {
    __shared__ unsigned short zs[256 * CPAD];
    __shared__ float scs[C_], offs[C_];
    int tid = threadIdx.x;
    int b = blockIdx.x >> 8;
    int pix0 = (blockIdx.x & 255) << 8;
    float m2 = stats[24 + b], r2 = stats[28 + b];
    if (tid < C_) {
        float sc = r2 * gn2w[tid];
        scs[tid] = sc;
        offs[tid] = gn2b[tid] - m2 * sc;
    }
    __syncthreads();
    {
        const short8* src = reinterpret_cast<const short8*>(
            &zb[(size_t)(b * NPIX + pix0 + tid) * C_]);
        short8 raw[12];
#pragma unroll
        for (int i = 0; i < 12; ++i) raw[i] = src[i];
        int lb = tid * CPAD;
#pragma unroll
        for (int i = 0; i < 12; ++i) {
            short8 pk;
#pragma unroll
            for (int j = 0; j < 8; ++j) {
                int c = i * 8 + j;
                float f = bf2f((unsigned short)raw[i][j]);
                pk[j] = (short)f2bf(fmaf(f, scs[c], offs[c]));
            }
            *reinterpret_cast<short8*>(&zs[lb + i * 8]) = pk;
        }
    }
    __syncthreads();
    int l = tid & 63, wv = tid >> 6;
    int bx = l & 15, cl = (l >> 4) * 8, q = l >> 4;
    short8 bfr[4][3];
#pragma unroll
    for (int nf = 0; nf < 4; ++nf) {
        int p = (4 * wv + nf) * 16 + bx;
#pragma unroll
        for (int kb = 0; kb < 3; ++kb)
            bfr[nf][kb] = *reinterpret_cast<const short8*>(&zs[p * CPAD + kb * 32 + cl]);
    }
    for (int mt = 0; mt < 6; ++mt) {
        int m0 = mt * 16;
        const unsigned short* wp = w3b + (m0 + bx) * C_ + cl;
        short8 af[3];
#pragma unroll
        for (int kb = 0; kb < 3; ++kb)
            af[kb] = *reinterpret_cast<const short8*>(wp + kb * 32);
        f32x4 acc[4];
#pragma unroll
        for (int nf = 0; nf < 4; ++nf) acc[nf] = (f32x4){0.f, 0.f, 0.f, 0.f};
#pragma unroll
        for (int nf = 0; nf < 4; ++nf)
#pragma unroll
            for (int kb = 0; kb < 3; ++kb)
                acc[nf] = mfma16(af[kb], bfr[nf][kb], acc[nf]);
        int o = m0 + q * 4;
#pragma unroll
        for (int nf = 0; nf < 4; ++nf) {
            int p = pix0 + (4 * wv + nf) * 16 + bx;
            size_t ob0 = (size_t)(b * C_ + o) * NPIX + p;
#pragma unroll
            for (int rg = 0; rg < 4; ++rg)
                out[ob0 + (size_t)rg * NPIX] = acc[nf][rg] + b3[o + rg];
        }
    }
}

extern "C" void kernel_launch(void* const* d_in, const int* in_sizes, int n_in,
                              void* d_out, int out_size, void* d_ws, size_t ws_size,
                              hipStream_t stream) {
    const float* x = (const float*)d_in[0];
    const float* w1 = (const float*)d_in[1];
    const float* b1 = (const float*)d_in[2];
    const float* w21 = (const float*)d_in[3];
    const float* b21 = (const float*)d_in[4];
    const float* w22 = (const float*)d_in[5];
    const float* b22 = (const float*)d_in[6];
    const float* w3 = (const float*)d_in[7];
    const float* b3 = (const float*)d_in[8];
    const float* gn1w = (const float*)d_in[9];
    const float* gn1b = (const float*)d_in[10];
    const float* gn2w = (const float*)d_in[11];
    const float* gn2b = (const float*)d_in[12];
    float* out = (float*)d_out;
    char* ws = (char*)d_ws;

    const size_t NB = (size_t)B_ * NPIX * C_ * sizeof(unsigned short);  // 50,331,648
    unsigned short* y1b = (unsigned short*)ws;
    unsigned short* zb = (unsigned short*)(ws + NB);
    float* stats = (float*)(ws + 2 * NB);  // 32 floats
    unsigned short* wb = (unsigned short*)(ws + 2 * NB + 128);
    unsigned short* w1b = wb;
    unsigned short* w21b = wb + C_ * C_;
    unsigned short* w22b = wb + 2 * C_ * C_;
    unsigned short* w3b = wb + 3 * C_ * C_;

    hipLaunchKernelGGL(k0_prep, dim3(144), dim3(256), 0, stream,
                       w1, w21, w22, w3, wb, stats);
    hipLaunchKernelGGL(k1_conv1, dim3(1024), dim3(256), 0, stream, x, w1b, b1, y1b, stats);
    hipLaunchKernelGGL(k2_fin, dim3(1), dim3(64), 0, stream, stats, 0, 16);
    hipLaunchKernelGGL(k3_main, dim3(1024), dim3(256), 0, stream,
                       y1b, w21b, b21, w22b, b22, gn1w, gn1b, zb, stats);
    hipLaunchKernelGGL(k2_fin, dim3(1), dim3(64), 0, stream, stats, 8, 24);
    hipLaunchKernelGGL(k5_conv3, dim3(1024), dim3(256), 0, stream,
                       zb, w3b, b3, gn2w, gn2b, out, stats);
}

// Round 4
// 230.134 us; speedup vs baseline: 2.5798x; 1.1431x over previous
//
#include <hip/hip_runtime.h>
#include <hip/hip_bf16.h>
#include <math.h>

// AxialShift block: conv1x1 -> GN(1) -> GELU -> 4 axial-shift conv1x1 branches
// (gelu, summed) -> GN(1) -> conv1x1.  B=4, C=96, H=W=256, fp32 in/out.
// Round 4: activations live in a zero-padded NHWC bf16 image [4][258][258][104]
// (ap). k1 writes pre-gelu y there; k2b gelu's it in place (once per element,
// BW-bound); k3 stages halos via global_load_lds (no VALU, 37.4KB LDS -> 4
// blocks/CU) and writes z fp32 NCHW into d_out; k5 does GN2+conv3 in-place.

#define B_ 4
#define C_ 96
#define H_ 256
#define W_ 256
#define NPIX (H_ * W_)
#define GN_N ((float)(C_ * NPIX))
#define CPAD 104           // channel stride in shorts (208 B, 16B-aligned)
#define PW 258             // padded image width/height
#define PIMG (PW * PW)     // 66564 pixels per padded image

// k3 tile
#define HT 8
#define WT 16
#define HHT (HT + 2)
#define HWT (WT + 2)
#define HALO_PX (HHT * HWT)          // 180
#define ROW_GR (HWT * CPAD * 2 / 16) // 234 granules (16B) per halo row
#define TOT_GR (HHT * ROW_GR)        // 2340
#define NLOADS ((TOT_GR + 63) / 64)  // 37

typedef __attribute__((ext_vector_type(4))) float f32x4;
typedef __attribute__((ext_vector_type(8))) short short8;

__device__ __forceinline__ unsigned short f2bf(float v) {
    unsigned int u = __float_as_uint(v);
    unsigned int r = (u + 0x7FFFu + ((u >> 16) & 1u)) >> 16;
    return (unsigned short)r;
}
__device__ __forceinline__ float bf2f(unsigned short u) {
    return __uint_as_float(((unsigned int)u) << 16);
}

__device__ __forceinline__ float gelu_f(float v) {
    // tanh-approx gelu = v * (1 - 1/(exp(2u)+1)); safe at +-inf
    float u2 = 1.5957691216057308f * v * (1.0f + 0.044715f * v * v);
    float e = __expf(u2);
    return v * (1.0f - 1.0f / (e + 1.0f));
}

__device__ __forceinline__ float waveReduceSum(float v) {
#pragma unroll
    for (int off = 32; off > 0; off >>= 1) v += __shfl_down(v, off);
    return v;
}

__device__ __forceinline__ f32x4 mfma16(short8 a, short8 b, f32x4 c) {
    return __builtin_amdgcn_mfma_f32_16x16x32_bf16(a, b, c, 0, 0, 0);
}

__device__ __forceinline__ void gload_lds16(const void* g, void* l) {
    __builtin_amdgcn_global_load_lds(
        (const __attribute__((address_space(1))) unsigned int*)g,
        (__attribute__((address_space(3))) unsigned int*)l, 16, 0, 0);
}

// ---------------- K0: weights -> bf16 [o][c], zero stats ----------------
__global__ void k0_prep(const float* __restrict__ w1, const float* __restrict__ w21,
                        const float* __restrict__ w22, const float* __restrict__ w3,
                        unsigned short* __restrict__ wb, float* __restrict__ stats) {
    int t = blockIdx.x * 256 + threadIdx.x;
    if (blockIdx.x == 0 && threadIdx.x < 16) stats[threadIdx.x] = 0.f;
    if (t >= 4 * C_ * C_) return;
    int m = t / (C_ * C_);
    int r = t - m * (C_ * C_);
    const float* src = (m == 0) ? w1 : (m == 1) ? w21 : (m == 2) ? w22 : w3;
    wb[t] = f2bf(src[r]);
}

// ------- K1: conv1 (MFMA) + GN1 stats -> ap interior (pre-gelu bf16) -------
__global__ __launch_bounds__(256, 3) void k1_conv1(
    const float* __restrict__ x, const unsigned short* __restrict__ w1b,
    const float* __restrict__ b1, unsigned short* __restrict__ ap,
    float* __restrict__ stats) {
    __shared__ unsigned short xs[256 * CPAD];
    __shared__ float red[8];
    int tid = threadIdx.x;
    int b = blockIdx.x >> 8;
    int h = blockIdx.x & 255;   // one image row per block
    int pix0 = h << 8;
    size_t xbase = (size_t)b * C_ * NPIX + pix0 + tid;
    int lb = tid * CPAD;
#pragma unroll
    for (int c0 = 0; c0 < C_; c0 += 8) {
        short8 pk;
#pragma unroll
        for (int j = 0; j < 8; ++j)
            pk[j] = (short)f2bf(x[xbase + (size_t)(c0 + j) * NPIX]);
        *reinterpret_cast<short8*>(&xs[lb + c0]) = pk;
    }
    __syncthreads();
    int l = tid & 63, wv = tid >> 6;
    int bx = l & 15, q = l >> 4, cl = q * 8;
    short8 bfr[4][3];
#pragma unroll
    for (int nf = 0; nf < 4; ++nf) {
        int p = (4 * wv + nf) * 16 + bx;
#pragma unroll
        for (int kb = 0; kb < 3; ++kb)
            bfr[nf][kb] = *reinterpret_cast<const short8*>(&xs[p * CPAD + kb * 32 + cl]);
    }
    unsigned int* xsu = reinterpret_cast<unsigned int*>(xs);
    float ls = 0.f, lsq = 0.f;
    for (int mt = 0; mt < 6; ++mt) {
        int m0 = mt * 16;
        const unsigned short* wp = w1b + (m0 + bx) * C_ + cl;
        short8 af[3];
#pragma unroll
        for (int kb = 0; kb < 3; ++kb)
            af[kb] = *reinterpret_cast<const short8*>(wp + kb * 32);
        f32x4 acc[4];
#pragma unroll
        for (int nf = 0; nf < 4; ++nf) acc[nf] = (f32x4){0.f, 0.f, 0.f, 0.f};
#pragma unroll
        for (int nf = 0; nf < 4; ++nf)
#pragma unroll
            for (int kb = 0; kb < 3; ++kb)
                acc[nf] = mfma16(af[kb], bfr[nf][kb], acc[nf]);
        int o = m0 + q * 4;
        float b0 = b1[o], b1v = b1[o + 1], b2v = b1[o + 2], b3v = b1[o + 3];
#pragma unroll
        for (int nf = 0; nf < 4; ++nf) {
            int p = (4 * wv + nf) * 16 + bx;  // own wave stripe: race-free
            float y0 = acc[nf][0] + b0, y1v = acc[nf][1] + b1v;
            float y2 = acc[nf][2] + b2v, y3 = acc[nf][3] + b3v;
            ls += y0 + y1v + y2 + y3;
            lsq += y0 * y0 + y1v * y1v + y2 * y2 + y3 * y3;
            xsu[p * (CPAD / 2) + (o >> 1)] =
                (unsigned int)f2bf(y0) | ((unsigned int)f2bf(y1v) << 16);
            xsu[p * (CPAD / 2) + (o >> 1) + 1] =
                (unsigned int)f2bf(y2) | ((unsigned int)f2bf(y3) << 16);
        }
    }
    __syncthreads();
    // dump to padded image: pixel (b, y=h+1, x=tid+1)
    size_t abase = ((size_t)b * PIMG + (size_t)(h + 1) * PW + 1 + tid) * CPAD;
#pragma unroll
    for (int c0 = 0; c0 < C_; c0 += 8)
        *reinterpret_cast<short8*>(&ap[abase + c0]) =
            *reinterpret_cast<short8*>(&xs[tid * CPAD + c0]);
    ls = waveReduceSum(ls);
    lsq = waveReduceSum(lsq);
    if (l == 0) { red[wv] = ls; red[4 + wv] = lsq; }
    __syncthreads();
    if (tid == 0) {
        atomicAdd(&stats[b], red[0] + red[1] + red[2] + red[3]);
        atomicAdd(&stats[4 + b], red[4] + red[5] + red[6] + red[7]);
    }
}

// ---------------- K2/K4: finalize GN stats ----------------
__global__ void k2_fin(float* stats, int so, int dof) {
    int t = threadIdx.x;
    if (t < 4) {
        float mean = stats[so + t] / GN_N;
        float var = stats[so + 4 + t] / GN_N - mean * mean;
        stats[dof + t] = mean;
        stats[dof + 4 + t] = rsqrtf(var + 1e-5f);
    }
}

// ------- K2b: in-place gelu(gn1-affine) on ap interior; zero border --------
__global__ __launch_bounds__(256) void k2b_gelu(
    unsigned short* __restrict__ ap, const float* __restrict__ gn1w,
    const float* __restrict__ gn1b, const float* __restrict__ stats) {
    __shared__ float scs[C_], offs[C_];
    int tid = threadIdx.x;
    int b = blockIdx.x / 261;                 // 261 blocks per image
    int pin = (blockIdx.x - b * 261) * 256 + tid;
    float m1 = stats[16 + b], r1 = stats[20 + b];
    if (tid < C_) {
        float sc = r1 * gn1w[tid];
        scs[tid] = sc;
        offs[tid] = gn1b[tid] - m1 * sc;
    }
    __syncthreads();
    if (pin >= PIMG) return;
    int y = pin / PW, xx = pin - y * PW;
    size_t base = ((size_t)b * PIMG + pin) * CPAD;
    if (y == 0 || y == PW - 1 || xx == 0 || xx == PW - 1) {
        short8 zz = (short8){0, 0, 0, 0, 0, 0, 0, 0};
#pragma unroll
        for (int i = 0; i < 12; ++i)
            *reinterpret_cast<short8*>(&ap[base + i * 8]) = zz;
    } else {
#pragma unroll
        for (int i = 0; i < 12; ++i) {
            short8 v = *reinterpret_cast<const short8*>(&ap[base + i * 8]);
            short8 pk;
#pragma unroll
            for (int j = 0; j < 8; ++j) {
                int c = i * 8 + j;
                float f = bf2f((unsigned short)v[j]);
                pk[j] = (short)f2bf(gelu_f(fmaf(f, scs[c], offs[c])));
            }
            *reinterpret_cast<short8*>(&ap[base + i * 8]) = pk;
        }
    }
}

// ---- K3: halo via global_load_lds, 4 shifted convs (MFMA), z->d_out fp32 ---
// shifts (s = kb-1): v0 a[h][w-s]  v1 a[h-s][w-s]  v2 a[h-s][w]  v3 a[h-s][w+s]
__global__ __launch_bounds__(256, 4) void k3_main(
    const unsigned short* __restrict__ ap,
    const unsigned short* __restrict__ w21b, const float* __restrict__ b21,
    const unsigned short* __restrict__ w22b, const float* __restrict__ b22,
    float* __restrict__ z, float* __restrict__ stats) {
    __shared__ unsigned short as_t[HALO_PX * CPAD];  // 37440 B
    __shared__ float red[8];
    int tid = threadIdx.x;
    int wseg = blockIdx.x & 15;
    int hseg = (blockIdx.x >> 4) & 31;
    int b = blockIdx.x >> 9;  // grid = 4*32*16 = 2048
    int l = tid & 63, wv = tid >> 6;
    int h0 = hseg * HT, w0 = wseg * WT;
    // --- stage halo (padded y rows h0..h0+9, padded x cols w0..w0+17) ---
    size_t ibase = ((size_t)b * PIMG + (size_t)h0 * PW + w0) * CPAD;  // shorts
    for (int i = wv; i < NLOADS; i += 4) {
        int g = i * 64 + l;
        unsigned int row = (unsigned int)g / ROW_GR;
        unsigned int off = (unsigned int)g - row * ROW_GR;
        const unsigned short* src = ap + ibase + (size_t)row * (PW * CPAD) + off * 8;
        if (g < TOT_GR) gload_lds16(src, &as_t[i * 512]);
    }
    __syncthreads();
    // --- compute ---
    int bx = l & 15, q = l >> 4, cl = q * 8;
    int Xb = (bx + 1) * CPAD + cl;
#define FR(R, dx, kb) (*reinterpret_cast<const short8*>( \
        &as_t[((R)*HWT + (dx)) * CPAD + Xb + (kb)*32]))
    float ls = 0.f, lsq = 0.f;
    for (int mt = 0; mt < 6; ++mt) {
        int m0 = mt * 16;
        const unsigned short* wpa = w21b + (m0 + bx) * C_ + cl;
        const unsigned short* wpb = w22b + (m0 + bx) * C_ + cl;
        short8 aA[3], aB[3];
#pragma unroll
        for (int kb = 0; kb < 3; ++kb) {
            aA[kb] = *reinterpret_cast<const short8*>(wpa + kb * 32);
            aB[kb] = *reinterpret_cast<const short8*>(wpb + kb * 32);
        }
        f32x4 acc[4][2];
#pragma unroll
        for (int v = 0; v < 4; ++v)
#pragma unroll
            for (int nf = 0; nf < 2; ++nf) acc[v][nf] = (f32x4){0.f, 0.f, 0.f, 0.f};
#pragma unroll
        for (int nf = 0; nf < 2; ++nf) {
            int r = 2 * wv + nf;  // output row in tile, 0..7
            // kb=0, s=-1
            {
                short8 f0 = FR(r + 1, 1, 0);
                short8 f1 = FR(r + 2, 1, 0);
                short8 f2 = FR(r + 2, 0, 0);
                short8 f3 = FR(r + 2, -1, 0);
                acc[0][nf] = mfma16(aA[0], f0, acc[0][nf]);
                acc[1][nf] = mfma16(aA[0], f1, acc[1][nf]);
                acc[2][nf] = mfma16(aB[0], f2, acc[2][nf]);
                acc[3][nf] = mfma16(aB[0], f3, acc[3][nf]);
            }
            // kb=1, s=0: all four variants share one frag
            {
                short8 fC = FR(r + 1, 0, 1);
                acc[0][nf] = mfma16(aA[1], fC, acc[0][nf]);
                acc[1][nf] = mfma16(aA[1], fC, acc[1][nf]);
                acc[2][nf] = mfma16(aB[1], fC, acc[2][nf]);
                acc[3][nf] = mfma16(aB[1], fC, acc[3][nf]);
            }
            // kb=2, s=+1
            {
                short8 f0 = FR(r + 1, -1, 2);
                short8 f1 = FR(r, -1, 2);
                short8 f2 = FR(r, 0, 2);
                short8 f3 = FR(r, 1, 2);
                acc[0][nf] = mfma16(aA[2], f0, acc[0][nf]);
                acc[1][nf] = mfma16(aA[2], f1, acc[1][nf]);
                acc[2][nf] = mfma16(aB[2], f2, acc[2][nf]);
                acc[3][nf] = mfma16(aB[2], f3, acc[3][nf]);
            }
        }
        const f32x4 bb1 = *reinterpret_cast<const f32x4*>(&b21[m0 + q * 4]);
        const f32x4 bb2 = *reinterpret_cast<const f32x4*>(&b22[m0 + q * 4]);
#pragma unroll
        for (int nf = 0; nf < 2; ++nf) {
            int hrow = h0 + 2 * wv + nf;
#pragma unroll
            for (int rg = 0; rg < 4; ++rg) {
                int o = m0 + q * 4 + rg;
                float zv = gelu_f(acc[0][nf][rg] + bb1[rg]) +
                           gelu_f(acc[1][nf][rg] + bb1[rg]) +
                           gelu_f(acc[2][nf][rg] + bb2[rg]) +
                           gelu_f(acc[3][nf][rg] + bb2[rg]);
                z[(size_t)(b * C_ + o) * NPIX + hrow * W_ + w0 + bx] = zv;
                ls += zv;
                lsq += zv * zv;
            }
        }
    }
#undef FR
    ls = waveReduceSum(ls);
    lsq = waveReduceSum(lsq);
    if (l == 0) { red[wv] = ls; red[4 + wv] = lsq; }
    __syncthreads();
    if (tid == 0) {
        atomicAdd(&stats[8 + b], red[0] + red[1] + red[2] + red[3]);
        atomicAdd(&stats[12 + b], red[4] + red[5] + red[6] + red[7]);
    }
}

// ------- K5: GN2 affine + conv3 (MFMA), in-place in d_out (NCHW fp32) ------
__global__ __launch_bounds__(256, 3) void k5_conv3(
    const unsigned short* __restrict__ w3b, const float* __restrict__ b3,
    const float* __restrict__ gn2w, const float* __restrict__ gn2b,
    float* __restrict__ zo, const float* __restrict__ stats) {
    __shared__ unsigned short zs[256 * CPAD];
    __shared__ float scs[C_], offs[C_];
    int tid = threadIdx.x;
    int b = blockIdx.x >> 8;
    int pix0 = (blockIdx.x & 255) << 8;
    float m2 = stats[24 + b], r2 = stats[28 + b];
    if (tid < C_) {
        float sc = r2 * gn2w[tid];
        scs[tid] = sc;
        offs[tid] = gn2b[tid] - m2 * sc;
    }
    __syncthreads();
    size_t zbase = (size_t)b * C_ * NPIX + pix0 + tid;
    int lb = tid * CPAD;
#pragma unroll
    for (int c0 = 0; c0 < C_; c0 += 8) {
        short8 pk;
#pragma unroll
        for (int j = 0; j < 8; ++j) {
            int c = c0 + j;
            pk[j] = (short)f2bf(fmaf(zo[zbase + (size_t)c * NPIX], scs[c], offs[c]));
        }
        *reinterpret_cast<short8*>(&zs[lb + c0]) = pk;
    }
    __syncthreads();
    int l = tid & 63, wv = tid >> 6;
    int bx = l & 15, q = l >> 4, cl = q * 8;
    short8 bfr[4][3];
#pragma unroll
    for (int nf = 0; nf < 4; ++nf) {
        int p = (4 * wv + nf) * 16 + bx;
#pragma unroll
        for (int kb = 0; kb < 3; ++kb)
            bfr[nf][kb] = *reinterpret_cast<const short8*>(&zs[p * CPAD + kb * 32 + cl]);
    }
    for (int mt = 0; mt < 6; ++mt) {
        int m0 = mt * 16;
        const unsigned short* wp = w3b + (m0 + bx) * C_ + cl;
        short8 af[3];
#pragma unroll
        for (int kb = 0; kb < 3; ++kb)
            af[kb] = *reinterpret_cast<const short8*>(wp + kb * 32);
        f32x4 acc[4];
#pragma unroll
        for (int nf = 0; nf < 4; ++nf) acc[nf] = (f32x4){0.f, 0.f, 0.f, 0.f};
#pragma unroll
        for (int nf = 0; nf < 4; ++nf)
#pragma unroll
            for (int kb = 0; kb < 3; ++kb)
                acc[nf] = mfma16(af[kb], bfr[nf][kb], acc[nf]);
        int o = m0 + q * 4;
        float b0 = b3[o], b1v = b3[o + 1], b2v = b3[o + 2], b3v = b3[o + 3];
#pragma unroll
        for (int nf = 0; nf < 4; ++nf) {
            int p = pix0 + (4 * wv + nf) * 16 + bx;
            size_t ob0 = (size_t)(b * C_ + o) * NPIX + p;
            zo[ob0] = acc[nf][0] + b0;
            zo[ob0 + NPIX] = acc[nf][1] + b1v;
            zo[ob0 + 2 * NPIX] = acc[nf][2] + b2v;
            zo[ob0 + 3 * NPIX] = acc[nf][3] + b3v;
        }
    }
}

extern "C" void kernel_launch(void* const* d_in, const int* in_sizes, int n_in,
                              void* d_out, int out_size, void* d_ws, size_t ws_size,
                              hipStream_t stream) {
    const float* x = (const float*)d_in[0];
    const float* w1 = (const float*)d_in[1];
    const float* b1 = (const float*)d_in[2];
    const float* w21 = (const float*)d_in[3];
    const float* b21 = (const float*)d_in[4];
    const float* w22 = (const float*)d_in[5];
    const float* b22 = (const float*)d_in[6];
    const float* w3 = (const float*)d_in[7];
    const float* b3 = (const float*)d_in[8];
    const float* gn1w = (const float*)d_in[9];
    const float* gn1b = (const float*)d_in[10];
    const float* gn2w = (const float*)d_in[11];
    const float* gn2b = (const float*)d_in[12];
    float* out = (float*)d_out;
    char* ws = (char*)d_ws;

    const size_t APB = (size_t)B_ * PIMG * CPAD * sizeof(unsigned short);  // 55,381,248
    unsigned short* ap = (unsigned short*)ws;
    float* stats = (float*)(ws + APB);  // 32 floats
    unsigned short* wb = (unsigned short*)(ws + APB + 128);
    unsigned short* w1b = wb;
    unsigned short* w21b = wb + C_ * C_;
    unsigned short* w22b = wb + 2 * C_ * C_;
    unsigned short* w3b = wb + 3 * C_ * C_;

    hipLaunchKernelGGL(k0_prep, dim3(144), dim3(256), 0, stream,
                       w1, w21, w22, w3, wb, stats);
    hipLaunchKernelGGL(k1_conv1, dim3(1024), dim3(256), 0, stream, x, w1b, b1, ap, stats);
    hipLaunchKernelGGL(k2_fin, dim3(1), dim3(64), 0, stream, stats, 0, 16);
    hipLaunchKernelGGL(k2b_gelu, dim3(B_ * 261), dim3(256), 0, stream,
                       ap, gn1w, gn1b, stats);
    hipLaunchKernelGGL(k3_main, dim3(2048), dim3(256), 0, stream,
                       ap, w21b, b21, w22b, b22, out, stats);
    hipLaunchKernelGGL(k2_fin, dim3(1), dim3(64), 0, stream, stats, 8, 24);
    hipLaunchKernelGGL(k5_conv3, dim3(1024), dim3(256), 0, stream,
                       w3b, b3, gn2w, gn2b, out, stats);
}

// Round 5
// 170.085 us; speedup vs baseline: 3.4906x; 1.3531x over previous
//
#include <hip/hip_runtime.h>
#include <hip/hip_bf16.h>
#include <math.h>

// AxialShift block: conv1x1 -> GN(1) -> GELU -> 4 axial-shift conv1x1 branches
// (gelu, summed) -> GN(1) -> conv1x1.  B=4, C=96, H=W=256, fp32 in/out.
// Round 5: k2b folded into k3's reg-staging (affine+gelu+border-mask in regs),
// rcp-based gelu (no IEEE div), activation frags hoisted across mt (ds_reads
// 144->18/thread), z stored bf16 NHWC in ws (k5 reads contiguous).
//   k0: weights->bf16, zero stats | k1: conv1+GN1 stats -> ap (NHWC bf16)
//   k2: finalize stats | k3: halo reg-stage + 4 shifted convs -> zb + GN2 stats
//   k5: GN2 affine + conv3 -> d_out (fp32 NCHW)

#define B_ 4
#define C_ 96
#define H_ 256
#define W_ 256
#define NPIX (H_ * W_)
#define GN_N ((float)(C_ * NPIX))
#define CPAD 104           // LDS channel stride in shorts (208B: 16B-aligned, 2-way banks)

// k3 tile
#define HT 8
#define WT 16
#define HHT (HT + 2)
#define HWT (WT + 2)
#define HALO_PX (HHT * HWT)     // 180
#define GR_PX 12                 // 16B granules per pixel (96 ch bf16)
#define ROW_GR (HWT * GR_PX)     // 216
#define TOT_GR (HHT * ROW_GR)    // 2160

typedef __attribute__((ext_vector_type(4))) float f32x4;
typedef __attribute__((ext_vector_type(8))) short short8;
typedef __attribute__((ext_vector_type(2))) unsigned int uint2v;

__device__ __forceinline__ unsigned short f2bf(float v) {
    unsigned int u = __float_as_uint(v);
    unsigned int r = (u + 0x7FFFu + ((u >> 16) & 1u)) >> 16;
    return (unsigned short)r;
}
__device__ __forceinline__ float bf2f(unsigned short u) {
    return __uint_as_float(((unsigned int)u) << 16);
}

__device__ __forceinline__ float gelu_f(float v) {
    // tanh-approx gelu = v*(1 - 1/(e+1)), e = exp(1.59577 v (1+0.044715 v^2))
    float t = fmaf(v * v, 0.07135481627f, 1.5957691216f);
    float e = __expf(v * t);
    float r = __builtin_amdgcn_rcpf(e + 1.0f);
    return v - v * r;
}

__device__ __forceinline__ float waveReduceSum(float v) {
#pragma unroll
    for (int off = 32; off > 0; off >>= 1) v += __shfl_down(v, off);
    return v;
}

__device__ __forceinline__ f32x4 mfma16(short8 a, short8 b, f32x4 c) {
    return __builtin_amdgcn_mfma_f32_16x16x32_bf16(a, b, c, 0, 0, 0);
}

// ---------------- K0: weights -> bf16 [o][c], zero stats ----------------
__global__ void k0_prep(const float* __restrict__ w1, const float* __restrict__ w21,
                        const float* __restrict__ w22, const float* __restrict__ w3,
                        unsigned short* __restrict__ wb, float* __restrict__ stats) {
    int t = blockIdx.x * 256 + threadIdx.x;
    if (blockIdx.x == 0 && threadIdx.x < 16) stats[threadIdx.x] = 0.f;
    if (t >= 4 * C_ * C_) return;
    int m = t / (C_ * C_);
    int r = t - m * (C_ * C_);
    const float* src = (m == 0) ? w1 : (m == 1) ? w21 : (m == 2) ? w22 : w3;
    wb[t] = f2bf(src[r]);
}

// ------- K1: conv1 (MFMA) + GN1 stats -> ap NHWC bf16 (pre-gelu) -----------
__global__ __launch_bounds__(256, 3) void k1_conv1(
    const float* __restrict__ x, const unsigned short* __restrict__ w1b,
    const float* __restrict__ b1, unsigned short* __restrict__ ap,
    float* __restrict__ stats) {
    __shared__ unsigned short xs[256 * CPAD];
    __shared__ float red[8];
    int tid = threadIdx.x;
    int b = blockIdx.x >> 8;
    int h = blockIdx.x & 255;
    int pix0 = h << 8;
    size_t xbase = (size_t)b * C_ * NPIX + pix0 + tid;
    int lb = tid * CPAD;
#pragma unroll
    for (int c0 = 0; c0 < C_; c0 += 8) {
        short8 pk;
#pragma unroll
        for (int j = 0; j < 8; ++j)
            pk[j] = (short)f2bf(x[xbase + (size_t)(c0 + j) * NPIX]);
        *reinterpret_cast<short8*>(&xs[lb + c0]) = pk;
    }
    __syncthreads();
    int l = tid & 63, wv = tid >> 6;
    int bx = l & 15, q = l >> 4, cl = q * 8;
    short8 bfr[4][3];
#pragma unroll
    for (int nf = 0; nf < 4; ++nf) {
        int p = (4 * wv + nf) * 16 + bx;
#pragma unroll
        for (int kb = 0; kb < 3; ++kb)
            bfr[nf][kb] = *reinterpret_cast<const short8*>(&xs[p * CPAD + kb * 32 + cl]);
    }
    unsigned int* xsu = reinterpret_cast<unsigned int*>(xs);
    float ls = 0.f, lsq = 0.f;
    for (int mt = 0; mt < 6; ++mt) {
        int m0 = mt * 16;
        const unsigned short* wp = w1b + (m0 + bx) * C_ + cl;
        short8 af[3];
#pragma unroll
        for (int kb = 0; kb < 3; ++kb)
            af[kb] = *reinterpret_cast<const short8*>(wp + kb * 32);
        f32x4 acc[4];
#pragma unroll
        for (int nf = 0; nf < 4; ++nf) acc[nf] = (f32x4){0.f, 0.f, 0.f, 0.f};
#pragma unroll
        for (int nf = 0; nf < 4; ++nf)
#pragma unroll
            for (int kb = 0; kb < 3; ++kb)
                acc[nf] = mfma16(af[kb], bfr[nf][kb], acc[nf]);
        int o = m0 + q * 4;
        float b0 = b1[o], b1v = b1[o + 1], b2v = b1[o + 2], b3v = b1[o + 3];
#pragma unroll
        for (int nf = 0; nf < 4; ++nf) {
            int p = (4 * wv + nf) * 16 + bx;  // own wave stripe: race-free
            float y0 = acc[nf][0] + b0, y1v = acc[nf][1] + b1v;
            float y2 = acc[nf][2] + b2v, y3 = acc[nf][3] + b3v;
            ls += y0 + y1v + y2 + y3;
            lsq += y0 * y0 + y1v * y1v + y2 * y2 + y3 * y3;
            xsu[p * (CPAD / 2) + (o >> 1)] =
                (unsigned int)f2bf(y0) | ((unsigned int)f2bf(y1v) << 16);
            xsu[p * (CPAD / 2) + (o >> 1) + 1] =
                (unsigned int)f2bf(y2) | ((unsigned int)f2bf(y3) << 16);
        }
    }
    __syncthreads();
    size_t abase = (size_t)(b * NPIX + pix0 + tid) * C_;
#pragma unroll
    for (int c0 = 0; c0 < C_; c0 += 8)
        *reinterpret_cast<short8*>(&ap[abase + c0]) =
            *reinterpret_cast<short8*>(&xs[tid * CPAD + c0]);
    ls = waveReduceSum(ls);
    lsq = waveReduceSum(lsq);
    if (l == 0) { red[wv] = ls; red[4 + wv] = lsq; }
    __syncthreads();
    if (tid == 0) {
        atomicAdd(&stats[b], red[0] + red[1] + red[2] + red[3]);
        atomicAdd(&stats[4 + b], red[4] + red[5] + red[6] + red[7]);
    }
}

// ---------------- K2/K4: finalize GN stats ----------------
__global__ void k2_fin(float* stats, int so, int dof) {
    int t = threadIdx.x;
    if (t < 4) {
        float mean = stats[so + t] / GN_N;
        float var = stats[so + 4 + t] / GN_N - mean * mean;
        stats[dof + t] = mean;
        stats[dof + 4 + t] = rsqrtf(var + 1e-5f);
    }
}

// ---- K3: halo reg-stage (affine+gelu+mask) + 4 shifted convs -> zb NHWC ----
// shifts (s = kb-1): v0 a[h][w-s]  v1 a[h-s][w-s]  v2 a[h-s][w]  v3 a[h-s][w+s]
__global__ __launch_bounds__(256, 4) void k3_main(
    const unsigned short* __restrict__ ap,
    const unsigned short* __restrict__ w21b, const float* __restrict__ b21,
    const unsigned short* __restrict__ w22b, const float* __restrict__ b22,
    const float* __restrict__ gn1w, const float* __restrict__ gn1b,
    unsigned short* __restrict__ zb, float* __restrict__ stats) {
    __shared__ unsigned short as_t[HALO_PX * CPAD];  // 37440 B
    __shared__ float red[8];
    __shared__ float scs[C_], offs[C_];
    int tid = threadIdx.x;
    int wseg = blockIdx.x & 15;
    int hseg = (blockIdx.x >> 4) & 31;
    int b = blockIdx.x >> 9;  // grid = 4*32*16 = 2048
    int l = tid & 63, wv = tid >> 6;
    int h0 = hseg * HT, w0 = wseg * WT;
    float m1 = stats[16 + b], r1 = stats[20 + b];
    if (tid < C_) {
        float sc = r1 * gn1w[tid];
        scs[tid] = sc;
        offs[tid] = gn1b[tid] - m1 * sc;
    }
    __syncthreads();
    // --- stage halo: coalesced b128 loads, affine+gelu+border-mask in regs ---
    for (int g = tid; g < TOT_GR; g += 256) {
        int row = g / ROW_GR;
        int rem = g - row * ROW_GR;
        int p = rem / GR_PX;
        int cgr = rem - p * GR_PX;
        int hh = h0 - 1 + row, ww = w0 - 1 + p;
        bool valid = ((unsigned)hh < (unsigned)H_) && ((unsigned)ww < (unsigned)W_);
        int hc = valid ? hh : 0, wc = valid ? ww : 0;
        short8 raw = *reinterpret_cast<const short8*>(
            &ap[(size_t)(b * NPIX + hc * W_ + wc) * C_ + cgr * 8]);
        short8 pk;
#pragma unroll
        for (int j = 0; j < 8; ++j) {
            int c = cgr * 8 + j;
            float f = bf2f((unsigned short)raw[j]);
            float gv = gelu_f(fmaf(f, scs[c], offs[c]));
            pk[j] = valid ? (short)f2bf(gv) : (short)0;
        }
        *reinterpret_cast<short8*>(&as_t[(row * HWT + p) * CPAD + cgr * 8]) = pk;
    }
    __syncthreads();
    // --- compute: frags hoisted per row, weights streamed from global(L2) ---
    int bx = l & 15, q = l >> 4, cl = q * 8;
    int Xb = (bx + 1) * CPAD + cl;
#define FR(R, dx, kb) (*reinterpret_cast<const short8*>( \
        &as_t[((R)*HWT + (dx)) * CPAD + Xb + (kb)*32]))
    float ls = 0.f, lsq = 0.f;
#pragma unroll
    for (int nf = 0; nf < 2; ++nf) {
        int r = 2 * wv + nf;  // output row in tile
        short8 f0a = FR(r + 1, 1, 0), f0b = FR(r + 2, 1, 0);
        short8 f0c = FR(r + 2, 0, 0), f0d = FR(r + 2, -1, 0);
        short8 fC = FR(r + 1, 0, 1);
        short8 f2a = FR(r + 1, -1, 2), f2b = FR(r, -1, 2);
        short8 f2c = FR(r, 0, 2), f2d = FR(r, 1, 2);
        size_t zpix = (size_t)(b * NPIX + (h0 + r) * W_ + w0 + bx) * C_;
        for (int mt = 0; mt < 6; ++mt) {
            int m0 = mt * 16;
            const unsigned short* wpa = w21b + (m0 + bx) * C_ + cl;
            const unsigned short* wpb = w22b + (m0 + bx) * C_ + cl;
            short8 aA0 = *reinterpret_cast<const short8*>(wpa);
            short8 aA1 = *reinterpret_cast<const short8*>(wpa + 32);
            short8 aA2 = *reinterpret_cast<const short8*>(wpa + 64);
            short8 aB0 = *reinterpret_cast<const short8*>(wpb);
            short8 aB1 = *reinterpret_cast<const short8*>(wpb + 32);
            short8 aB2 = *reinterpret_cast<const short8*>(wpb + 64);
            f32x4 a0 = (f32x4){0.f, 0.f, 0.f, 0.f}, a1 = a0, a2 = a0, a3 = a0;
            a0 = mfma16(aA0, f0a, a0);
            a1 = mfma16(aA0, f0b, a1);
            a2 = mfma16(aB0, f0c, a2);
            a3 = mfma16(aB0, f0d, a3);
            a0 = mfma16(aA1, fC, a0);
            a1 = mfma16(aA1, fC, a1);
            a2 = mfma16(aB1, fC, a2);
            a3 = mfma16(aB1, fC, a3);
            a0 = mfma16(aA2, f2a, a0);
            a1 = mfma16(aA2, f2b, a1);
            a2 = mfma16(aB2, f2c, a2);
            a3 = mfma16(aB2, f2d, a3);
            const f32x4 bb1 = *reinterpret_cast<const f32x4*>(&b21[m0 + q * 4]);
            const f32x4 bb2 = *reinterpret_cast<const f32x4*>(&b22[m0 + q * 4]);
            float zv[4];
#pragma unroll
            for (int rg = 0; rg < 4; ++rg) {
                float z0 = gelu_f(a0[rg] + bb1[rg]) + gelu_f(a1[rg] + bb1[rg]) +
                           gelu_f(a2[rg] + bb2[rg]) + gelu_f(a3[rg] + bb2[rg]);
                zv[rg] = z0;
                ls += z0;
                lsq += z0 * z0;
            }
            uint2v pk;
            pk.x = (unsigned int)f2bf(zv[0]) | ((unsigned int)f2bf(zv[1]) << 16);
            pk.y = (unsigned int)f2bf(zv[2]) | ((unsigned int)f2bf(zv[3]) << 16);
            *reinterpret_cast<uint2v*>(&zb[zpix + m0 + q * 4]) = pk;
        }
    }
#undef FR
    ls = waveReduceSum(ls);
    lsq = waveReduceSum(lsq);
    if (l == 0) { red[wv] = ls; red[4 + wv] = lsq; }
    __syncthreads();
    if (tid == 0) {
        atomicAdd(&stats[8 + b], red[0] + red[1] + red[2] + red[3]);
        atomicAdd(&stats[12 + b], red[4] + red[5] + red[6] + red[7]);
    }
}

// ------- K5: GN2 affine + conv3 (MFMA) -> d_out (fp32 NCHW) ----------------
__global__ __launch_bounds__(256, 3) void k5_conv3(
    const unsigned short* __restrict__ zb,
    const unsigned short* __restrict__ w3b, const float* __restrict__ b3,
    const float* __restrict__ gn2w, const float* __restrict__ gn2b,
    float* __restrict__ out, const float* __restrict__ stats) {
    __shared__ unsigned short zs[256 * CPAD];
    __shared__ float scs[C_], offs[C_];
    int tid = threadIdx.x;
    int b = blockIdx.x >> 8;
    int pix0 = (blockIdx.x & 255) << 8;
    float m2 = stats[24 + b], r2 = stats[28 + b];
    if (tid < C_) {
        float sc = r2 * gn2w[tid];
        scs[tid] = sc;
        offs[tid] = gn2b[tid] - m2 * sc;
    }
    __syncthreads();
    {
        const short8* src = reinterpret_cast<const short8*>(
            &zb[(size_t)(b * NPIX + pix0 + tid) * C_]);
        int lb = tid * CPAD;
#pragma unroll
        for (int i = 0; i < 12; ++i) {
            short8 v = src[i];
            short8 pk;
#pragma unroll
            for (int j = 0; j < 8; ++j) {
                int c = i * 8 + j;
                pk[j] = (short)f2bf(fmaf(bf2f((unsigned short)v[j]), scs[c], offs[c]));
            }
            *reinterpret_cast<short8*>(&zs[lb + i * 8]) = pk;
        }
    }
    __syncthreads();
    int l = tid & 63, wv = tid >> 6;
    int bx = l & 15, q = l >> 4, cl = q * 8;
    short8 bfr[4][3];
#pragma unroll
    for (int nf = 0; nf < 4; ++nf) {
        int p = (4 * wv + nf) * 16 + bx;
#pragma unroll
        for (int kb = 0; kb < 3; ++kb)
            bfr[nf][kb] = *reinterpret_cast<const short8*>(&zs[p * CPAD + kb * 32 + cl]);
    }
    for (int mt = 0; mt < 6; ++mt) {
        int m0 = mt * 16;
        const unsigned short* wp = w3b + (m0 + bx) * C_ + cl;
        short8 af[3];
#pragma unroll
        for (int kb = 0; kb < 3; ++kb)
            af[kb] = *reinterpret_cast<const short8*>(wp + kb * 32);
        f32x4 acc[4];
#pragma unroll
        for (int nf = 0; nf < 4; ++nf) acc[nf] = (f32x4){0.f, 0.f, 0.f, 0.f};
#pragma unroll
        for (int nf = 0; nf < 4; ++nf)
#pragma unroll
            for (int kb = 0; kb < 3; ++kb)
                acc[nf] = mfma16(af[kb], bfr[nf][kb], acc[nf]);
        int o = m0 + q * 4;
        float b0 = b3[o], b1v = b3[o + 1], b2v = b3[o + 2], b3v = b3[o + 3];
#pragma unroll
        for (int nf = 0; nf < 4; ++nf) {
            int p = pix0 + (4 * wv + nf) * 16 + bx;
            size_t ob0 = (size_t)(b * C_ + o) * NPIX + p;
            out[ob0] = acc[nf][0] + b0;
            out[ob0 + NPIX] = acc[nf][1] + b1v;
            out[ob0 + 2 * NPIX] = acc[nf][2] + b2v;
            out[ob0 + 3 * NPIX] = acc[nf][3] + b3v;
        }
    }
}

extern "C" void kernel_launch(void* const* d_in, const int* in_sizes, int n_in,
                              void* d_out, int out_size, void* d_ws, size_t ws_size,
                              hipStream_t stream) {
    const float* x = (const float*)d_in[0];
    const float* w1 = (const float*)d_in[1];
    const float* b1 = (const float*)d_in[2];
    const float* w21 = (const float*)d_in[3];
    const float* b21 = (const float*)d_in[4];
    const float* w22 = (const float*)d_in[5];
    const float* b22 = (const float*)d_in[6];
    const float* w3 = (const float*)d_in[7];
    const float* b3 = (const float*)d_in[8];
    const float* gn1w = (const float*)d_in[9];
    const float* gn1b = (const float*)d_in[10];
    const float* gn2w = (const float*)d_in[11];
    const float* gn2b = (const float*)d_in[12];
    float* out = (float*)d_out;
    char* ws = (char*)d_ws;

    const size_t NB = (size_t)B_ * NPIX * C_ * sizeof(unsigned short);  // 50,331,648
    unsigned short* ap = (unsigned short*)ws;
    unsigned short* zb = (unsigned short*)(ws + NB);
    float* stats = (float*)(ws + 2 * NB);  // 32 floats
    unsigned short* wb = (unsigned short*)(ws + 2 * NB + 128);
    unsigned short* w1b = wb;
    unsigned short* w21b = wb + C_ * C_;
    unsigned short* w22b = wb + 2 * C_ * C_;
    unsigned short* w3b = wb + 3 * C_ * C_;

    hipLaunchKernelGGL(k0_prep, dim3(144), dim3(256), 0, stream,
                       w1, w21, w22, w3, wb, stats);
    hipLaunchKernelGGL(k1_conv1, dim3(1024), dim3(256), 0, stream, x, w1b, b1, ap, stats);
    hipLaunchKernelGGL(k2_fin, dim3(1), dim3(64), 0, stream, stats, 0, 16);
    hipLaunchKernelGGL(k3_main, dim3(2048), dim3(256), 0, stream,
                       ap, w21b, b21, w22b, b22, gn1w, gn1b, zb, stats);
    hipLaunchKernelGGL(k2_fin, dim3(1), dim3(64), 0, stream, stats, 8, 24);
    hipLaunchKernelGGL(k5_conv3, dim3(1024), dim3(256), 0, stream,
                       zb, w3b, b3, gn2w, gn2b, out, stats);
}